// Round 1
// baseline (361.422 us; speedup 1.0000x reference)
//
#include <hip/hip_runtime.h>
#include <hip/hip_bf16.h>

typedef short v8s __attribute__((ext_vector_type(8)));
typedef float v4f __attribute__((ext_vector_type(4)));
typedef unsigned short u16;

#define PROW 58
#define PCOL 64

// ws layout:
//   A:  [cc 8][n 32][row 58][col 64][32 ch] bf16, XOR-swizzled in ch-quads by col
//   Wb: [kk 9][cc 8][oc 256][32 ic] bf16, XOR-swizzled in ic-quads by oc
static constexpr size_t A_CC_STRIDE = (size_t)32 * PROW * PCOL * 32;   // 3,801,088 elems
static constexpr size_t A_ELEMS     = 8 * A_CC_STRIDE;                 // 30,408,704
static constexpr size_t A_BYTES     = A_ELEMS * 2;                     // 60,817,408 B
static constexpr size_t WB_ELEMS    = (size_t)9 * 8 * 256 * 32;        // 589,824

__device__ __forceinline__ void gl2lds16(const void* gptr, void* lptr) {
  auto g = (const __attribute__((address_space(1))) unsigned int*)gptr;
  auto l = (__attribute__((address_space(3))) unsigned int*)lptr;
  __builtin_amdgcn_global_load_lds(g, l, 16, 0, 0);
}

// ---------------- kernel 1: golay * FWHT * RMSNorm -> swizzled bf16 ----------------
__global__ __launch_bounds__(256) void fwht_kernel(
    const float* __restrict__ x, const float* __restrict__ rms_w,
    __hip_bfloat16* __restrict__ A)
{
  __shared__ float tile[256 * 57];   // [ch][x], +1 pad
  const int tid = threadIdx.x;
  const int y = blockIdx.x;
  const int n = blockIdx.y;
  const float* src = x + (size_t)n * 256 * 3136 + (size_t)y * 56;
  for (int f = tid; f < 256 * 56; f += 256) {
    int ch = f / 56;
    int xx = f - ch * 56;
    tile[ch * 57 + xx] = src[(size_t)ch * 3136 + xx];
  }
  __syncthreads();
  const int lane = tid & 63;
  const int wv = tid >> 6;
  float gs[4], rw[4];
  #pragma unroll
  for (int k = 0; k < 4; k++) {
    int ch = lane + 64 * k;
    // golay(ch) = (-1)^popcount(ch & (ch>>1))  (Rudin-Shapiro)
    gs[k] = 1.0f - 2.0f * (float)(__popc(ch & (ch >> 1)) & 1);
    rw[k] = rms_w[ch];
  }
  const int icq = (lane >> 3) & 3;
  const int jj = lane & 7;
  for (int p = wv; p < 56; p += 4) {
    float v[4];
    #pragma unroll
    for (int k = 0; k < 4; k++)
      v[k] = tile[(lane + 64 * k) * 57 + p] * gs[k];
    // FWHT stages h=1..32 across lanes (ch bit h == lane bit h)
    #pragma unroll
    for (int hs = 0; hs < 6; hs++) {
      const int h = 1 << hs;
      #pragma unroll
      for (int k = 0; k < 4; k++) {
        float o = __shfl_xor(v[k], h, 64);
        v[k] = ((lane & h) ? -v[k] : v[k]) + o;
      }
    }
    // h=64: pairs (v0,v1),(v2,v3); h=128: pairs (v0,v2),(v1,v3)
    { float a=v[0], b=v[1], c=v[2], d=v[3];
      v[0]=a+b; v[1]=a-b; v[2]=c+d; v[3]=c-d; }
    { float a=v[0], b=v[1], c=v[2], d=v[3];
      v[0]=a+c; v[2]=a-c; v[1]=b+d; v[3]=b-d; }
    // RMS over 256 channels
    float ss = v[0]*v[0] + v[1]*v[1] + v[2]*v[2] + v[3]*v[3];
    #pragma unroll
    for (int hs = 0; hs < 6; hs++) ss += __shfl_xor(ss, 1 << hs, 64);
    float sc = rsqrtf(ss * (1.0f / 256.0f) + 1e-5f);
    const int col = p + 1, row = y + 1;
    const int sw = (col >> 1) & 3;
    const int icq_st = icq ^ sw;
    #pragma unroll
    for (int k = 0; k < 4; k++) {
      int cc = (lane + 64 * k) >> 5;
      size_t off = ((((size_t)cc * 32 + n) * PROW + row) * PCOL + col) * 32 + icq_st * 8 + jj;
      A[off] = __float2bfloat16(v[k] * sc * rw[k]);
    }
  }
}

// ---------------- kernel 2: W fp32 -> swizzled bf16 ----------------
__global__ __launch_bounds__(256) void wconv_kernel(
    const float* __restrict__ Wf, __hip_bfloat16* __restrict__ Wb)
{
  int t = blockIdx.x * 256 + threadIdx.x;    // linear dst index
  int j = t & 7;
  int icq_st = (t >> 3) & 3;
  int oc = (t >> 5) & 255;
  int cc = (t >> 13) & 7;
  int kk = t >> 16;
  int icq = icq_st ^ ((oc >> 1) & 3);
  int ic = cc * 32 + icq * 8 + j;
  int ky = kk / 3, kx = kk - ky * 3;
  float w = Wf[((oc * 256 + ic) * 3 + ky) * 3 + kx];
  Wb[t] = __float2bfloat16(w);
}

// ---------------- kernel 3: implicit-GEMM conv via MFMA ----------------
__global__ __launch_bounds__(256, 3) void conv_kernel(
    const u16* __restrict__ A, const u16* __restrict__ Wb,
    const float* __restrict__ bias, float* __restrict__ out)
{
  __shared__ __align__(16) u16 As[4 * PCOL * 32];   // 16 KB: rows y0..y0+3 (padded), 64 cols, 32 ch
  __shared__ __align__(16) u16 Bs[2][128 * 32];     // 2 x 8 KB, double buffered

  const int tid  = threadIdx.x;
  const int lane = tid & 63;
  const int wv   = tid >> 6;
  const int wm   = wv & 1;        // wave M half (output row within pair)
  const int wn   = wv >> 1;       // wave N half
  const int m15  = lane & 15;
  const int q    = lane >> 4;

  const int ocb = blockIdx.x;     // oc half (0/1)
  const int y0  = blockIdx.y * 2; // output row pair
  const int n   = blockIdx.z;

  const u16* gA = A + ((size_t)n * PROW + y0) * (PCOL * 32);

  v4f acc[4][4];
  const v4f vzero = {0.0f, 0.0f, 0.0f, 0.0f};
  #pragma unroll
  for (int i = 0; i < 4; i++)
    #pragma unroll
    for (int j = 0; j < 4; j++)
      acc[i][j] = vzero;

  // B fragment LDS offsets (in u16), independent of cc/kk
  int ub[4];
  #pragma unroll
  for (int nf = 0; nf < 4; nf++) {
    int ocl = wn * 64 + nf * 16 + m15;
    ub[nf] = (ocl * 4 + (q ^ ((ocl >> 1) & 3))) * 8;
  }

  auto stageA = [&](int cc) {
    const u16* g = gA + (size_t)cc * A_CC_STRIDE + tid * 8;
    u16* d = As + tid * 8;
    #pragma unroll
    for (int k = 0; k < 4; k++)
      gl2lds16(g + k * 2048, d + k * 2048);
  };
  auto stageB = [&](int cc, int kk, int pb) {
    const u16* g = Wb + ((kk * 8 + cc) * 8192 + ocb * 4096) + tid * 8;
    u16* d = &Bs[pb][0] + tid * 8;
    #pragma unroll
    for (int k = 0; k < 2; k++)
      gl2lds16(g + k * 2048, d + k * 2048);
  };

  stageA(0);
  stageB(0, 0, 0);
  __syncthreads();

  for (int cc = 0; cc < 8; cc++) {
    for (int kk = 0; kk < 9; kk++) {
      const int pb = kk & 1;
      if (kk < 8) stageB(cc, kk + 1, pb ^ 1);     // prefetch next tap
      const int ky = kk / 3;
      const int kx = kk - ky * 3;
      const int irow = wm + ky;                   // staged padded row
      v8s af[4];
      #pragma unroll
      for (int mf = 0; mf < 4; mf++) {
        int col = mf * 16 + m15 + kx;             // up to 65 on dead lanes
        col = col > 63 ? 63 : col;                // clamp (dead cols never stored)
        int u = (irow * PCOL + col) * 4 + (q ^ ((col >> 1) & 3));
        af[mf] = *(const v8s*)(As + u * 8);
      }
      const u16* bsb = &Bs[pb][0];
      v8s bfr[4];
      #pragma unroll
      for (int nf = 0; nf < 4; nf++)
        bfr[nf] = *(const v8s*)(bsb + ub[nf]);
      #pragma unroll
      for (int mf = 0; mf < 4; mf++)
        #pragma unroll
        for (int nf = 0; nf < 4; nf++)
          acc[mf][nf] = __builtin_amdgcn_mfma_f32_16x16x32_bf16(af[mf], bfr[nf], acc[mf][nf], 0, 0, 0);
      if (kk < 8) __syncthreads();
    }
    if (cc < 7) {
      __syncthreads();          // all waves done reading As & Bs[0]
      stageA(cc + 1);
      stageB(cc + 1, 0, 0);
      __syncthreads();
    }
  }

  // epilogue: C/D layout col(lane&15)=oc, row(q*4+reg)=x; float4 over regs = 4 consecutive x
  const int yrow = y0 + wm;
  #pragma unroll
  for (int nf = 0; nf < 4; nf++) {
    const int oc = ocb * 128 + wn * 64 + nf * 16 + m15;
    const float bb = bias[oc];
    float* orow = out + ((size_t)(n * 256 + oc) * 56 + yrow) * 56;
    #pragma unroll
    for (int mf = 0; mf < 4; mf++) {
      const int c0 = mf * 16 + q * 4;
      if (c0 < 56) {
        v4f val = acc[mf][nf];
        val.x += bb; val.y += bb; val.z += bb; val.w += bb;
        *(v4f*)(orow + c0) = val;
      }
    }
  }
}

extern "C" void kernel_launch(void* const* d_in, const int* in_sizes, int n_in,
                              void* d_out, int out_size, void* d_ws, size_t ws_size,
                              hipStream_t stream)
{
  const float* x     = (const float*)d_in[0];
  const float* Wf    = (const float*)d_in[1];
  const float* bias  = (const float*)d_in[2];
  const float* rms_w = (const float*)d_in[3];
  float* out = (float*)d_out;

  if (ws_size < A_BYTES + WB_ELEMS * 2) return;  // insufficient workspace -> fail loudly

  __hip_bfloat16* Abf = (__hip_bfloat16*)d_ws;
  __hip_bfloat16* Wb  = (__hip_bfloat16*)((char*)d_ws + A_BYTES);

  // zero halos (rows 0/57, cols 0,57..63) — ws is poisoned each call
  hipMemsetAsync(d_ws, 0, A_BYTES, stream);
  fwht_kernel<<<dim3(56, 32), 256, 0, stream>>>(x, rms_w, Abf);
  wconv_kernel<<<dim3((int)(WB_ELEMS / 256)), 256, 0, stream>>>(Wf, Wb);
  conv_kernel<<<dim3(2, 28, 32), 256, 0, stream>>>(
      (const u16*)Abf, (const u16*)Wb, bias, out);
}

// Round 2
// 342.256 us; speedup vs baseline: 1.0560x; 1.0560x over previous
//
#include <hip/hip_runtime.h>
#include <hip/hip_bf16.h>

typedef short v8s __attribute__((ext_vector_type(8)));
typedef float v4f __attribute__((ext_vector_type(4)));
typedef float v16f __attribute__((ext_vector_type(16)));
typedef unsigned short u16;

#define PROW 58
#define PCOL 64

// ws layout:
//   A:  [cc 8][n 32][row 58][col 64][32 ch] bf16, XOR-swizzled in ch-octets by col
//   Wb: [kk 9][cc 8][oc 256][32 ic] bf16, XOR-swizzled in ic-octets by oc
static constexpr size_t A_CC_STRIDE = (size_t)32 * PROW * PCOL * 32;   // elems
static constexpr size_t A_BYTES     = 8 * A_CC_STRIDE * 2;
static constexpr size_t WB_ELEMS    = (size_t)9 * 8 * 256 * 32;

__device__ __forceinline__ void gl2lds16(const void* gptr, void* lptr) {
  auto g = (const __attribute__((address_space(1))) unsigned int*)gptr;
  auto l = (__attribute__((address_space(3))) unsigned int*)lptr;
  __builtin_amdgcn_global_load_lds(g, l, 16, 0, 0);
}

__device__ __forceinline__ u16 f2bf(float f) {
  __hip_bfloat16 h = __float2bfloat16(f);
  union { __hip_bfloat16 b; u16 u; } cv; cv.b = h; return cv.u;
}

// ---------------- kernel 1: golay * FWHT * RMSNorm -> swizzled bf16 (+halo zeros) ----------------
__global__ __launch_bounds__(256, 2) void fwht_kernel(
    const float* __restrict__ x, const float* __restrict__ rms_w,
    u16* __restrict__ A)
{
  __shared__ __align__(16) char smem[58368];   // 256*57 floats, reused as u16 out-stage
  float* tile = (float*)smem;
  u16*   ob   = (u16*)smem;                    // [cc 8][p 56][32], cc stride 1808 (bank skew)

  const int tid = threadIdx.x;
  const int y = blockIdx.x;
  const int n = blockIdx.y;
  const float* src = x + (size_t)n * 256 * 3136 + (size_t)y * 56;
  for (int f = tid; f < 256 * 56; f += 256) {
    int ch = f / 56;
    int xx = f - ch * 56;
    tile[ch * 57 + xx] = src[(size_t)ch * 3136 + xx];
  }
  __syncthreads();

  const int lane = tid & 63;
  const int wv = tid >> 6;
  float gs[4], rw[4];
  #pragma unroll
  for (int k = 0; k < 4; k++) {
    int ch = lane + 64 * k;
    gs[k] = 1.0f - 2.0f * (float)(__popc(ch & (ch >> 1)) & 1);   // Rudin-Shapiro
    rw[k] = rms_w[ch];
  }

  unsigned int res[14][2];
  #pragma unroll
  for (int i = 0; i < 14; i++) {
    const int p = wv + 4 * i;
    float v[4];
    #pragma unroll
    for (int k = 0; k < 4; k++)
      v[k] = tile[(lane + 64 * k) * 57 + p] * gs[k];
    #pragma unroll
    for (int hs = 0; hs < 6; hs++) {
      const int h = 1 << hs;
      #pragma unroll
      for (int k = 0; k < 4; k++) {
        float o = __shfl_xor(v[k], h, 64);
        v[k] = ((lane & h) ? -v[k] : v[k]) + o;
      }
    }
    { float a=v[0], b=v[1], c=v[2], d=v[3];
      v[0]=a+b; v[1]=a-b; v[2]=c+d; v[3]=c-d; }
    { float a=v[0], b=v[1], c=v[2], d=v[3];
      v[0]=a+c; v[2]=a-c; v[1]=b+d; v[3]=b-d; }
    float ss = v[0]*v[0] + v[1]*v[1] + v[2]*v[2] + v[3]*v[3];
    #pragma unroll
    for (int hs = 0; hs < 6; hs++) ss += __shfl_xor(ss, 1 << hs, 64);
    float sc = rsqrtf(ss * (1.0f / 256.0f) + 1e-5f);
    res[i][0] = (unsigned int)f2bf(v[0] * sc * rw[0]) |
                ((unsigned int)f2bf(v[1] * sc * rw[1]) << 16);
    res[i][1] = (unsigned int)f2bf(v[2] * sc * rw[2]) |
                ((unsigned int)f2bf(v[3] * sc * rw[3]) << 16);
  }
  __syncthreads();   // all tile reads done; reuse smem as u16 out-stage

  const int icq = (lane >> 3) & 3;
  const int jj = lane & 7;
  const int ccl = lane >> 5;
  #pragma unroll
  for (int i = 0; i < 14; i++) {
    const int p = wv + 4 * i;
    const int sw = ((p + 1) >> 1) & 3;
    const int qs = (icq ^ sw) * 8 + jj;
    #pragma unroll
    for (int k = 0; k < 4; k++) {
      const int cc = 2 * k + ccl;
      u16 val = (u16)(res[i][k >> 1] >> (16 * (k & 1)));
      ob[cc * 1808 + p * 32 + qs] = val;
    }
  }
  __syncthreads();

  // copy out: per cc, cols 1..56 are one contiguous 3584-B run
  const int row = y + 1;
  #pragma unroll
  for (int i = 0; i < 7; i++) {
    int c = tid + 256 * i;               // 1792 chunks of 8 u16
    int cc = c / 224, rem = c - cc * 224;
    v8s val = *(const v8s*)(ob + cc * 1808 + rem * 8);
    size_t go = (((size_t)cc * 32 + n) * PROW + row) * 2048 + 32 + rem * 8;
    *(v8s*)(A + go) = val;
  }
  // halo cols 0 and 57..63 of this row
  {
    const v8s z = {0,0,0,0,0,0,0,0};
    int cc = tid >> 5, s = tid & 31;
    size_t rb = (((size_t)cc * 32 + n) * PROW + row) * 2048;
    if (s < 4) *(v8s*)(A + rb + s * 8) = z;
    else       *(v8s*)(A + rb + 57 * 32 + (s - 4) * 8) = z;
  }
  // halo rows 0 / 57
  if (y == 0 || y == 55) {
    const v8s z = {0,0,0,0,0,0,0,0};
    const int r = (y == 0) ? 0 : 57;
    #pragma unroll
    for (int i = 0; i < 8; i++) {
      int c = tid + 256 * i;             // 2048 chunks
      int cc = c >> 8, rem = c & 255;
      size_t go = (((size_t)cc * 32 + n) * PROW + r) * 2048 + rem * 8;
      *(v8s*)(A + go) = z;
    }
  }
}

// ---------------- kernel 2: W fp32 -> swizzled bf16 ----------------
__global__ __launch_bounds__(256) void wconv_kernel(
    const float* __restrict__ Wf, u16* __restrict__ Wb)
{
  int t = blockIdx.x * 256 + threadIdx.x;
  int j = t & 7;
  int icq_st = (t >> 3) & 3;
  int oc = (t >> 5) & 255;
  int cc = (t >> 13) & 7;
  int kk = t >> 16;
  int icq = icq_st ^ ((oc >> 1) & 3);
  int ic = cc * 32 + icq * 8 + j;
  int ky = kk / 3, kx = kk - ky * 3;
  float w = Wf[((oc * 256 + ic) * 3 + ky) * 3 + kx];
  Wb[t] = f2bf(w);
}

// ---------------- kernel 3: implicit-GEMM conv, 32x32x16 MFMA, 3-tap B staging ----------------
__global__ __launch_bounds__(256, 3) void conv_kernel(
    const u16* __restrict__ A, const u16* __restrict__ Wb,
    const float* __restrict__ bias, float* __restrict__ out)
{
  __shared__ __align__(16) u16 As[4 * PCOL * 32];     // 16 KB: 4 padded rows
  __shared__ __align__(16) u16 Bs[3 * 128 * 32];      // 24 KB: 3 taps (one ky row)

  const int tid  = threadIdx.x;
  const int lane = tid & 63;
  const int wv   = tid >> 6;
  const int wm   = wv & 1;          // output row within pair
  const int wn   = wv >> 1;         // oc 64-half
  const int m31  = lane & 31;
  const int kh8  = lane >> 5;       // k-octet selector

  const int ocb = blockIdx.x;
  const int y0  = blockIdx.y * 2;
  const int n   = blockIdx.z;

  const u16* gA = A + ((size_t)n * PROW + y0) * 2048;

  v16f acc[2][2];
  #pragma unroll
  for (int i = 0; i < 2; i++)
    #pragma unroll
    for (int j = 0; j < 2; j++)
      #pragma unroll
      for (int e = 0; e < 16; e++)
        acc[i][j][e] = 0.0f;

  // B fragment LDS offsets (u16 idx within a tap's 4096 block)
  int ub[2][2];
  #pragma unroll
  for (int nf = 0; nf < 2; nf++)
    #pragma unroll
    for (int kh = 0; kh < 2; kh++) {
      int ocl = wn * 64 + nf * 32 + m31;
      int q = kh * 2 + kh8;
      ub[nf][kh] = (ocl * 4 + (q ^ ((ocl >> 1) & 3))) * 8;
    }

  auto stageA = [&](int cc) {
    const u16* g = gA + (size_t)cc * A_CC_STRIDE + tid * 8;
    u16* d = As + tid * 8;
    #pragma unroll
    for (int k = 0; k < 4; k++)
      gl2lds16(g + k * 2048, d + k * 2048);
  };
  auto stageB = [&](int cc, int ky) {
    #pragma unroll
    for (int kx = 0; kx < 3; kx++) {
      const int kk = ky * 3 + kx;
      const u16* g = Wb + ((kk * 8 + cc) * 8192 + ocb * 4096) + tid * 8;
      u16* d = Bs + kx * 4096 + tid * 8;
      gl2lds16(g, d);
      gl2lds16(g + 2048, d + 2048);
    }
  };

  for (int cc = 0; cc < 8; cc++) {
    __syncthreads();
    stageA(cc);
    stageB(cc, 0);
    __syncthreads();
    #pragma unroll
    for (int ky = 0; ky < 3; ky++) {
      #pragma unroll
      for (int kx = 0; kx < 3; kx++) {
        v8s af[2][2];
        #pragma unroll
        for (int mf = 0; mf < 2; mf++)
          #pragma unroll
          for (int kh = 0; kh < 2; kh++) {
            int col = mf * 32 + m31 + kx;
            col = col > 63 ? 63 : col;          // dead cols (>=56) never stored
            int q = kh * 2 + kh8;
            int ua = (((wm + ky) * PCOL + col) * 4 + (q ^ ((col >> 1) & 3))) * 8;
            af[mf][kh] = *(const v8s*)(As + ua);
          }
        v8s bf[2][2];
        const u16* bsb = Bs + kx * 4096;
        #pragma unroll
        for (int nf = 0; nf < 2; nf++)
          #pragma unroll
          for (int kh = 0; kh < 2; kh++)
            bf[nf][kh] = *(const v8s*)(bsb + ub[nf][kh]);
        #pragma unroll
        for (int mf = 0; mf < 2; mf++)
          #pragma unroll
          for (int nf = 0; nf < 2; nf++) {
            acc[mf][nf] = __builtin_amdgcn_mfma_f32_32x32x16_bf16(af[mf][0], bf[nf][0], acc[mf][nf], 0, 0, 0);
            acc[mf][nf] = __builtin_amdgcn_mfma_f32_32x32x16_bf16(af[mf][1], bf[nf][1], acc[mf][nf], 0, 0, 0);
          }
      }
      if (ky < 2) {
        __syncthreads();
        stageB(cc, ky + 1);
        __syncthreads();
      }
    }
  }

  // epilogue: C/D 32x32: col(lane&31)=oc, row = (reg&3) + 8*(reg>>2) + 4*(lane>>5) = x
  const int yrow = y0 + wm;
  #pragma unroll
  for (int nf = 0; nf < 2; nf++) {
    const int oc = ocb * 128 + wn * 64 + nf * 32 + m31;
    const float bb = bias[oc];
    float* orow = out + ((size_t)(n * 256 + oc) * 56 + yrow) * 56;
    #pragma unroll
    for (int mf = 0; mf < 2; mf++) {
      #pragma unroll
      for (int g = 0; g < 4; g++) {
        const int x0 = mf * 32 + 8 * g + 4 * kh8;
        if (x0 < 56) {
          v4f val = { acc[mf][nf][4*g+0] + bb, acc[mf][nf][4*g+1] + bb,
                      acc[mf][nf][4*g+2] + bb, acc[mf][nf][4*g+3] + bb };
          *(v4f*)(orow + x0) = val;
        }
      }
    }
  }
}

extern "C" void kernel_launch(void* const* d_in, const int* in_sizes, int n_in,
                              void* d_out, int out_size, void* d_ws, size_t ws_size,
                              hipStream_t stream)
{
  const float* x     = (const float*)d_in[0];
  const float* Wf    = (const float*)d_in[1];
  const float* bias  = (const float*)d_in[2];
  const float* rms_w = (const float*)d_in[3];
  float* out = (float*)d_out;

  if (ws_size < A_BYTES + WB_ELEMS * 2) return;

  u16* Abf = (u16*)d_ws;
  u16* Wb  = (u16*)((char*)d_ws + A_BYTES);

  fwht_kernel<<<dim3(56, 32), 256, 0, stream>>>(x, rms_w, Abf);
  wconv_kernel<<<dim3((int)(WB_ELEMS / 256)), 256, 0, stream>>>(Wf, Wb);
  conv_kernel<<<dim3(2, 28, 32), 256, 0, stream>>>(Abf, Wb, bias, out);
}